// Round 3
// baseline (665.009 us; speedup 1.0000x reference)
//
#include <hip/hip_runtime.h>
#include <hip/hip_bf16.h>

#define LOG_2PI 1.8378770664093453f
#define R0 256        // rows resident in LDS triangle (multiple of 32)
#define GSTRIDE 512   // floats per global tail row
#define GROWS 256     // tail rows capacity per block
#define TRI_FLOATS 33280   // tribase(256)
#define SMEM_BYTES 137376  // 33280*4 + 512*4 + 512*4 + 32*4 + 8*4

// packed triangle: row r occupies [tribase(r), tribase(r)+ceil((r+1)/4)*4)
__device__ __forceinline__ int tribase(int r) {
    int m = r & 3;
    return r * (r + 1) / 2 + 6 * (r >> 2) + ((m * (7 - m)) >> 1);
}

// ---------------------------------------------------------------------------
__global__ __launch_bounds__(256) void build_A(const float* __restrict__ logd,
                                               const float* __restrict__ lt,
                                               float* __restrict__ A) {
    int idx = blockIdx.x * 256 + threadIdx.x;
    int i = idx >> 9, j = idx & 511;
    float v;
    if (j < i)       v = lt[(i * (i - 1)) / 2 + j];
    else if (j == i) v = expf(logd[i]);
    else             v = 0.f;
    A[idx] = v;
}

__global__ __launch_bounds__(256) void aat(const float* __restrict__ A,
                                           float* __restrict__ C) {
    __shared__ float Ash[32][33];
    __shared__ float Bsh[32][33];
    int tx = threadIdx.x & 31, ty = threadIdx.x >> 5;
    int bi = blockIdx.y, bj = blockIdx.x;
    float acc[4] = {0.f, 0.f, 0.f, 0.f};
    for (int k0 = 0; k0 < 512; k0 += 32) {
        #pragma unroll
        for (int q = 0; q < 4; q++) {
            int r = ty + q * 8;
            Ash[r][tx] = A[(bi * 32 + r) * 512 + k0 + tx];
            Bsh[r][tx] = A[(bj * 32 + r) * 512 + k0 + tx];
        }
        __syncthreads();
        for (int c = 0; c < 32; c++) {
            float bv = Bsh[tx][c];
            #pragma unroll
            for (int q = 0; q < 4; q++) acc[q] += Ash[ty + q * 8][c] * bv;
        }
        __syncthreads();
    }
    #pragma unroll
    for (int q = 0; q < 4; q++)
        C[(bi * 32 + ty + q * 8) * 512 + bj * 32 + tx] = acc[q];
}

__global__ __launch_bounds__(256) void compact(const float* __restrict__ x,
                                               const float* __restrict__ mu,
                                               const int* __restrict__ mask,
                                               int* __restrict__ obs_idx,
                                               int* __restrict__ n_obs,
                                               float* __restrict__ rc) {
    int b = blockIdx.x, t = threadIdx.x;
    __shared__ int wsum[4];
    int i0 = 2 * t, i1 = 2 * t + 1;
    int m0 = (mask[b * 512 + i0] != 0) ? 1 : 0;
    int m1 = (mask[b * 512 + i1] != 0) ? 1 : 0;
    int local = m0 + m1;
    int v = local;
    int lane = t & 63, wv = t >> 6;
    #pragma unroll
    for (int off = 1; off < 64; off <<= 1) {
        int u = __shfl_up(v, off, 64);
        if (lane >= off) v += u;
    }
    if (lane == 63) wsum[wv] = v;
    __syncthreads();
    int woff = 0;
    for (int w = 0; w < wv; w++) woff += wsum[w];
    int excl = woff + v - local;
    if (m0) { obs_idx[b * 512 + excl] = i0; rc[b * 512 + excl] = x[b * 512 + i0] - mu[i0]; }
    if (m1) { int p = excl + m0; obs_idx[b * 512 + p] = i1; rc[b * 512 + p] = x[b * 512 + i1] - mu[i1]; }
    if (t == 0) n_obs[b] = wsum[0] + wsum[1] + wsum[2] + wsum[3];
}

// ---------------------------------------------------------------------------
// Diag-block Cholesky + z-panel solve, wave0 lanes 0..31, rows via rptr().
// ---------------------------------------------------------------------------
template <typename RPF>
__device__ __forceinline__ void diag_block(RPF rptr, float* zsh, float* dinv,
                                           float& llog, int j0, int nb, int n, int tid) {
    if (tid < 32) {
        int l = tid;
        int r = j0 + l;
        float a[32];
        float z = 0.f;
        if (r < n) {
            const float4* src = (const float4*)(rptr(r) + j0);
            #pragma unroll
            for (int q = 0; q < 8; q++) {
                float4 t = src[q];
                a[4*q+0] = t.x; a[4*q+1] = t.y; a[4*q+2] = t.z; a[4*q+3] = t.w;
            }
            z = zsh[r];
        } else {
            #pragma unroll
            for (int q = 0; q < 32; q++) a[q] = 0.f;
        }
        float dv = 0.f;
        #pragma unroll
        for (int k = 0; k < 32; k++) {
            if (k < nb) {
                float akk = __shfl(a[k], k, 64);
                float lkk = sqrtf(akk);
                float rin = 1.f / lkk;
                if (l == k) { dv = rin; llog += logf(lkk); }
                a[k] = (l == k) ? lkk : a[k] * rin;
                #pragma unroll
                for (int j = k + 1; j < 32; j++) {
                    float ajk = __shfl(a[k], j, 64);
                    a[j] -= a[k] * ajk;
                }
            }
        }
        #pragma unroll
        for (int k = 0; k < 32; k++) {
            if (k < nb) {
                if (l == k) z *= dv;
                float zk = __shfl(z, k, 64);
                if (l > k) z -= a[k] * zk;
            }
        }
        dinv[l] = dv;
        if (l < nb) {            // equivalent to r < n here
            zsh[r] = z;
            float* dst = rptr(r) + j0;
            #pragma unroll
            for (int c = 0; c < 32; c++)
                if (c <= l) dst[c] = a[c];
        }
    }
}

// ---------------------------------------------------------------------------
// Fused gather + in-LDS blocked Cholesky + forward solve + NLL.
// One 256-thread block per sample. Rows < R0 in packed LDS triangle;
// rows >= R0 (tail, rare/small) in per-block global buffer.
// ---------------------------------------------------------------------------
__global__ __launch_bounds__(256, 1) void chol_solve(
    const float* __restrict__ cov, const float* __restrict__ rc,
    const int* __restrict__ obs_idx, const int* __restrict__ n_obs,
    float* __restrict__ gtail_all, float* __restrict__ out) {

    extern __shared__ float smem[];
    float* T    = smem;                         // 33280 floats
    float* zsh  = T + TRI_FLOATS;               // 512
    int*   oi   = (int*)(zsh + 512);            // 512
    float* dinv = (float*)(oi + 512);           // 32
    float* red  = dinv + 32;                    // 8

    int b = blockIdx.x, tid = threadIdx.x;
    int lane = tid & 63, wv = tid >> 6;
    int n = n_obs[b]; if (n > 512) n = 512;
    float* gtail = gtail_all + (size_t)b * GROWS * GSTRIDE;

    if (n == 0) { if (tid == 0) out[b] = 0.f; return; }

    for (int i = tid; i < n; i += 256) {
        oi[i] = obs_idx[b * 512 + i];
        zsh[i] = rc[b * 512 + i];
    }
    __syncthreads();

    // ---- gather (once): lane = column, ascending oi -> coalesced-ish ----
    for (int r = wv; r < n; r += 4) {
        const float* crow = cov + (size_t)oi[r] * 512;
        if (r < R0) {
            float* dst = T + tribase(r);
            for (int j = lane; j <= r; j += 64) dst[j] = crow[oi[j]];
        } else {
            float* dst = gtail + (size_t)(r - R0) * GSTRIDE;
            for (int j = lane; j <= r; j += 64) dst[j] = crow[oi[j]];
        }
    }
    __syncthreads();

    float llog = 0.f;

    for (int j0 = 0; j0 < n; j0 += 32) {
        int nb = min(32, n - j0);
        int m = n - j0 - 32;          // trailing rows (may be <= 0)

        // ---------------- diag + z panel ----------------
        if (j0 + 32 <= R0) {
            diag_block([&](int r) { return T + tribase(r); },
                       zsh, dinv, llog, j0, nb, n, tid);
        } else {
            diag_block([&](int r) { return gtail + (size_t)(r - R0) * GSTRIDE; },
                       zsh, dinv, llog, j0, nb, n, tid);
        }
        __syncthreads();

        // ---------------- trsm rows + z-update ----------------
        if (m > 0) {   // nb == 32 here
            for (int idx = tid; idx < m; idx += 256) {
                int r = j0 + 32 + idx;
                float p[32];
                if (r < R0) {
                    const float4* s = (const float4*)(T + tribase(r) + j0);
                    #pragma unroll
                    for (int q = 0; q < 8; q++) {
                        float4 t = s[q];
                        p[4*q+0] = t.x; p[4*q+1] = t.y; p[4*q+2] = t.z; p[4*q+3] = t.w;
                    }
                } else {
                    const float4* s = (const float4*)(gtail + (size_t)(r - R0) * GSTRIDE + j0);
                    #pragma unroll
                    for (int q = 0; q < 8; q++) {
                        float4 t = s[q];
                        p[4*q+0] = t.x; p[4*q+1] = t.y; p[4*q+2] = t.z; p[4*q+3] = t.w;
                    }
                }
                if (j0 + 32 <= R0) {
                    #pragma unroll
                    for (int j = 0; j < 32; j++) {
                        float acc = p[j];
                        const float4* dj = (const float4*)(T + tribase(j0 + j) + j0);
                        #pragma unroll
                        for (int q = 0; 4 * q < j; q++) {
                            float4 t = dj[q];
                            int c = 4 * q;
                            if (c + 0 < j) acc -= p[c+0] * t.x;
                            if (c + 1 < j) acc -= p[c+1] * t.y;
                            if (c + 2 < j) acc -= p[c+2] * t.z;
                            if (c + 3 < j) acc -= p[c+3] * t.w;
                        }
                        p[j] = acc * dinv[j];
                    }
                } else {
                    #pragma unroll
                    for (int j = 0; j < 32; j++) {
                        float acc = p[j];
                        const float4* dj = (const float4*)(gtail + (size_t)(j0 + j - R0) * GSTRIDE + j0);
                        #pragma unroll
                        for (int q = 0; 4 * q < j; q++) {
                            float4 t = dj[q];
                            int c = 4 * q;
                            if (c + 0 < j) acc -= p[c+0] * t.x;
                            if (c + 1 < j) acc -= p[c+1] * t.y;
                            if (c + 2 < j) acc -= p[c+2] * t.z;
                            if (c + 3 < j) acc -= p[c+3] * t.w;
                        }
                        p[j] = acc * dinv[j];
                    }
                }
                if (r < R0) {
                    float4* d = (float4*)(T + tribase(r) + j0);
                    #pragma unroll
                    for (int q = 0; q < 8; q++)
                        d[q] = make_float4(p[4*q+0], p[4*q+1], p[4*q+2], p[4*q+3]);
                } else {
                    float4* d = (float4*)(gtail + (size_t)(r - R0) * GSTRIDE + j0);
                    #pragma unroll
                    for (int q = 0; q < 8; q++)
                        d[q] = make_float4(p[4*q+0], p[4*q+1], p[4*q+2], p[4*q+3]);
                }
                float zu = 0.f;
                #pragma unroll
                for (int q = 0; q < 8; q++) {
                    float4 zz = *(const float4*)&zsh[j0 + 4 * q];
                    zu += p[4*q+0] * zz.x + p[4*q+1] * zz.y + p[4*q+2] * zz.z + p[4*q+3] * zz.w;
                }
                zsh[r] -= zu;
            }
        }
        __syncthreads();

        // ---------------- syrk trailing update ----------------
        if (m > 0) {
            int iLim = (n < R0) ? n : R0;
            int m1 = iLim - (j0 + 32);
            if (m1 > 0) {
                int T8 = (m1 + 7) >> 3;
                int ntile = T8 * (T8 + 1) / 2;
                for (int e = tid; e < ntile; e += 256) {
                    int ti = (int)((sqrtf(8.f * (float)e + 1.f) - 1.f) * 0.5f);
                    while ((ti + 1) * (ti + 2) / 2 <= e) ti++;
                    while (ti * (ti + 1) / 2 > e) ti--;
                    int tj = e - ti * (ti + 1) / 2;
                    int ib = j0 + 32 + ti * 8, jb = j0 + 32 + tj * 8;
                    int bA[8], bB[8];
                    #pragma unroll
                    for (int a = 0; a < 8; a++) {
                        bA[a] = tribase(min(ib + a, iLim - 1)) + j0;
                        bB[a] = tribase(min(jb + a, iLim - 1)) + j0;
                    }
                    float acc[8][8];
                    #pragma unroll
                    for (int a = 0; a < 8; a++)
                        #pragma unroll
                        for (int c = 0; c < 8; c++) acc[a][c] = 0.f;
                    #pragma unroll
                    for (int qk = 0; qk < 8; qk++) {
                        float4 av[8], bvv[8];
                        #pragma unroll
                        for (int a = 0; a < 8; a++)
                            av[a] = *(const float4*)(T + bA[a] + 4 * qk);
                        #pragma unroll
                        for (int c = 0; c < 8; c++)
                            bvv[c] = *(const float4*)(T + bB[c] + 4 * qk);
                        #pragma unroll
                        for (int a = 0; a < 8; a++)
                            #pragma unroll
                            for (int c = 0; c < 8; c++)
                                acc[a][c] += av[a].x * bvv[c].x + av[a].y * bvv[c].y +
                                             av[a].z * bvv[c].z + av[a].w * bvv[c].w;
                    }
                    #pragma unroll
                    for (int a = 0; a < 8; a++) {
                        int i = ib + a;
                        if (i < iLim) {
                            float* trow = T + tribase(i);
                            if (jb + 7 <= i) {
                                float4* d = (float4*)(trow + jb);
                                float4 v0 = d[0], v1 = d[1];
                                v0.x -= acc[a][0]; v0.y -= acc[a][1];
                                v0.z -= acc[a][2]; v0.w -= acc[a][3];
                                v1.x -= acc[a][4]; v1.y -= acc[a][5];
                                v1.z -= acc[a][6]; v1.w -= acc[a][7];
                                d[0] = v0; d[1] = v1;
                            } else {
                                #pragma unroll
                                for (int c = 0; c < 8; c++) {
                                    int j = jb + c;
                                    if (j <= i) trow[j] -= acc[a][c];
                                }
                            }
                        }
                    }
                }
            }
            // tail rows (>= R0): 1x8 tasks, A from gtail, B from LDS or gtail
            int tS = (R0 > j0 + 32) ? R0 : (j0 + 32);
            if (n > tS) {
                int tl = n - tS;
                int CB = (n - (j0 + 32) + 7) >> 3;
                int ntask = tl * CB;
                for (int t = tid; t < ntask; t += 256) {
                    int irow = tS + t / CB;
                    int cb = t % CB;
                    int jb = j0 + 32 + cb * 8;
                    if (jb > irow) continue;
                    const float* gA = gtail + (size_t)(irow - R0) * GSTRIDE + j0;
                    float pa[32];
                    #pragma unroll
                    for (int q = 0; q < 8; q++) {
                        float4 t4 = *(const float4*)(gA + 4 * q);
                        pa[4*q+0] = t4.x; pa[4*q+1] = t4.y; pa[4*q+2] = t4.z; pa[4*q+3] = t4.w;
                    }
                    float av[8];
                    #pragma unroll
                    for (int c = 0; c < 8; c++) av[c] = 0.f;
                    if (jb + 8 <= R0) {
                        #pragma unroll
                        for (int c = 0; c < 8; c++) {
                            int j = jb + c;
                            if (j <= irow) {
                                const float4* dj = (const float4*)(T + tribase(j) + j0);
                                float s = 0.f;
                                #pragma unroll
                                for (int q = 0; q < 8; q++) {
                                    float4 t4 = dj[q];
                                    s += pa[4*q+0] * t4.x + pa[4*q+1] * t4.y +
                                         pa[4*q+2] * t4.z + pa[4*q+3] * t4.w;
                                }
                                av[c] = s;
                            }
                        }
                    } else {
                        #pragma unroll
                        for (int c = 0; c < 8; c++) {
                            int j = jb + c;
                            if (j <= irow) {
                                const float4* dj = (const float4*)(gtail + (size_t)(j - R0) * GSTRIDE + j0);
                                float s = 0.f;
                                #pragma unroll
                                for (int q = 0; q < 8; q++) {
                                    float4 t4 = dj[q];
                                    s += pa[4*q+0] * t4.x + pa[4*q+1] * t4.y +
                                         pa[4*q+2] * t4.z + pa[4*q+3] * t4.w;
                                }
                                av[c] = s;
                            }
                        }
                    }
                    float* gw = gtail + (size_t)(irow - R0) * GSTRIDE;
                    #pragma unroll
                    for (int c = 0; c < 8; c++) {
                        int j = jb + c;
                        if (j <= irow) gw[j] -= av[c];
                    }
                }
                __threadfence_block();
            }
        }
        __syncthreads();
    }

    // ---------------- epilogue: quad + logdet reduce ----------------
    float q = 0.f;
    for (int i = tid; i < n; i += 256) { float zv = zsh[i]; q += zv * zv; }
    #pragma unroll
    for (int off = 32; off; off >>= 1) {
        q    += __shfl_down(q, off, 64);
        llog += __shfl_down(llog, off, 64);
    }
    if (lane == 0) { red[wv] = q; red[4 + wv] = llog; }
    __syncthreads();
    if (tid == 0) {
        float qt = red[0] + red[1] + red[2] + red[3];
        float ls = red[4] + red[5] + red[6] + red[7];
        out[b] = 0.5f * (qt + 2.f * ls + (float)n * LOG_2PI);
    }
}

// ---------------------------------------------------------------------------
// ws: [0,1M) cov | [1M,2M) A | n_obs | obs_idx | rc | gtail (256*512 f32/block)
// ---------------------------------------------------------------------------
extern "C" void kernel_launch(void* const* d_in, const int* in_sizes, int n_in,
                              void* d_out, int out_size, void* d_ws, size_t ws_size,
                              hipStream_t stream) {
    const float* x    = (const float*)d_in[0];
    const float* mu   = (const float*)d_in[1];
    const float* logd = (const float*)d_in[2];
    const float* lt   = (const float*)d_in[3];
    const int*   mask = (const int*)d_in[4];
    float* out = (float*)d_out;

    char* ws = (char*)d_ws;
    float* cov     = (float*)(ws);
    float* A       = (float*)(ws + 1048576);
    int*   n_obs   = (int*)  (ws + 2097152);
    int*   obs_idx = (int*)  (ws + 2098176);
    float* rc      = (float*)(ws + 2622464);
    float* gtail   = (float*)(ws + 3146752);

    (void)hipFuncSetAttribute((const void*)chol_solve,
                              hipFuncAttributeMaxDynamicSharedMemorySize,
                              SMEM_BYTES);

    build_A<<<1024, 256, 0, stream>>>(logd, lt, A);
    dim3 g(16, 16);
    aat<<<g, 256, 0, stream>>>(A, cov);
    compact<<<256, 256, 0, stream>>>(x, mu, mask, obs_idx, n_obs, rc);
    chol_solve<<<256, 256, SMEM_BYTES, stream>>>(cov, rc, obs_idx, n_obs, gtail, out);
}

// Round 4
// 596.251 us; speedup vs baseline: 1.1153x; 1.1153x over previous
//
#include <hip/hip_runtime.h>
#include <hip/hip_bf16.h>

#define LOG_2PI 1.8378770664093453f
#define R0 256        // rows resident in LDS triangle
#define GSTRIDE 512   // floats per global tail row
#define GROWS 256
#define TRI_FLOATS 33280       // tribase(256)
#define SSTR 36                // staging row stride (16B aligned)
#define SMEM_FLOATS (TRI_FLOATS + 512 + 512 + 32 + 8 + 64*SSTR)
#define SMEM_BYTES (SMEM_FLOATS * 4)   // 146592

// packed triangle: row r at [tribase(r)], padded to 16B-aligned row starts
__device__ __forceinline__ int tribase(int r) {
    int m = r & 3;
    return r * (r + 1) / 2 + 6 * (r >> 2) + ((m * (7 - m)) >> 1);
}

// ---------------------------------------------------------------------------
__global__ __launch_bounds__(256) void build_A(const float* __restrict__ logd,
                                               const float* __restrict__ lt,
                                               float* __restrict__ A) {
    int idx = blockIdx.x * 256 + threadIdx.x;
    int i = idx >> 9, j = idx & 511;
    float v;
    if (j < i)       v = lt[(i * (i - 1)) / 2 + j];
    else if (j == i) v = expf(logd[i]);
    else             v = 0.f;
    A[idx] = v;
}

// cov = A A^T, 64x64 macro per block, lower-triangle blocks + mirror writes.
__global__ __launch_bounds__(256) void aat64(const float* __restrict__ A,
                                             float* __restrict__ C) {
    __shared__ __align__(16) float Ash[64 * SSTR];
    __shared__ __align__(16) float Bsh[64 * SSTR];
    int tid = threadIdx.x;
    int e = blockIdx.x;
    int bi = (int)((sqrtf(8.f * (float)e + 1.f) - 1.f) * 0.5f);
    while ((bi + 1) * (bi + 2) / 2 <= e) bi++;
    while (bi * (bi + 1) / 2 > e) bi--;
    int bj = e - bi * (bi + 1) / 2;
    int ty = tid >> 4, tx = tid & 15;
    float acc[4][4];
    #pragma unroll
    for (int a = 0; a < 4; a++)
        #pragma unroll
        for (int c = 0; c < 4; c++) acc[a][c] = 0.f;
    for (int k0 = 0; k0 < 512; k0 += 32) {
        __syncthreads();
        for (int t = tid; t < 512; t += 256) {
            int rr = t >> 3, f = t & 7;
            *(float4*)&Ash[rr * SSTR + f * 4] =
                *(const float4*)&A[(size_t)(bi * 64 + rr) * 512 + k0 + f * 4];
            *(float4*)&Bsh[rr * SSTR + f * 4] =
                *(const float4*)&A[(size_t)(bj * 64 + rr) * 512 + k0 + f * 4];
        }
        __syncthreads();
        #pragma unroll
        for (int q = 0; q < 8; q++) {
            float4 av[4], bv[4];
            #pragma unroll
            for (int a = 0; a < 4; a++) av[a] = *(const float4*)&Ash[(ty * 4 + a) * SSTR + q * 4];
            #pragma unroll
            for (int c = 0; c < 4; c++) bv[c] = *(const float4*)&Bsh[(tx * 4 + c) * SSTR + q * 4];
            #pragma unroll
            for (int a = 0; a < 4; a++)
                #pragma unroll
                for (int c = 0; c < 4; c++)
                    acc[a][c] += av[a].x * bv[c].x + av[a].y * bv[c].y +
                                 av[a].z * bv[c].z + av[a].w * bv[c].w;
        }
    }
    #pragma unroll
    for (int a = 0; a < 4; a++)
        #pragma unroll
        for (int c = 0; c < 4; c++) {
            int i = bi * 64 + ty * 4 + a, j = bj * 64 + tx * 4 + c;
            C[(size_t)i * 512 + j] = acc[a][c];
            if (bi != bj) C[(size_t)j * 512 + i] = acc[a][c];
        }
}

__global__ __launch_bounds__(256) void compact(const float* __restrict__ x,
                                               const float* __restrict__ mu,
                                               const int* __restrict__ mask,
                                               int* __restrict__ obs_idx,
                                               int* __restrict__ n_obs,
                                               float* __restrict__ rc) {
    int b = blockIdx.x, t = threadIdx.x;
    __shared__ int wsum[4];
    int i0 = 2 * t, i1 = 2 * t + 1;
    int m0 = (mask[b * 512 + i0] != 0) ? 1 : 0;
    int m1 = (mask[b * 512 + i1] != 0) ? 1 : 0;
    int local = m0 + m1;
    int v = local;
    int lane = t & 63, wv = t >> 6;
    #pragma unroll
    for (int off = 1; off < 64; off <<= 1) {
        int u = __shfl_up(v, off, 64);
        if (lane >= off) v += u;
    }
    if (lane == 63) wsum[wv] = v;
    __syncthreads();
    int woff = 0;
    for (int w = 0; w < wv; w++) woff += wsum[w];
    int excl = woff + v - local;
    if (m0) { obs_idx[b * 512 + excl] = i0; rc[b * 512 + excl] = x[b * 512 + i0] - mu[i0]; }
    if (m1) { int p = excl + m0; obs_idx[b * 512 + p] = i1; rc[b * 512 + p] = x[b * 512 + i1] - mu[i1]; }
    if (t == 0) n_obs[b] = wsum[0] + wsum[1] + wsum[2] + wsum[3];
}

// ---------------------------------------------------------------------------
// Diag-block Cholesky + z-panel solve, wave0 lanes 0..31.
// ---------------------------------------------------------------------------
template <typename RPF>
__device__ __forceinline__ void diag_block(RPF rptr, float* zsh, float* dinv,
                                           float& llog, int j0, int nb, int n, int tid) {
    if (tid < 32) {
        int l = tid;
        int r = j0 + l;
        float a[32];
        float z = 0.f;
        if (r < n) {
            const float4* src = (const float4*)(rptr(r) + j0);
            #pragma unroll
            for (int q = 0; q < 8; q++) {
                float4 t = src[q];
                a[4*q+0] = t.x; a[4*q+1] = t.y; a[4*q+2] = t.z; a[4*q+3] = t.w;
            }
            z = zsh[r];
        } else {
            #pragma unroll
            for (int q = 0; q < 32; q++) a[q] = 0.f;
        }
        float dv = 0.f;
        #pragma unroll
        for (int k = 0; k < 32; k++) {
            if (k < nb) {
                float akk = __shfl(a[k], k, 64);
                float lkk = sqrtf(akk);
                float rin = 1.f / lkk;
                if (l == k) { dv = rin; llog += logf(lkk); }
                a[k] = (l == k) ? lkk : a[k] * rin;
                #pragma unroll
                for (int j = k + 1; j < 32; j++) {
                    float ajk = __shfl(a[k], j, 64);
                    a[j] -= a[k] * ajk;
                }
            }
        }
        #pragma unroll
        for (int k = 0; k < 32; k++) {
            if (k < nb) {
                if (l == k) z *= dv;
                float zk = __shfl(z, k, 64);
                if (l > k) z -= a[k] * zk;
            }
        }
        dinv[l] = dv;
        if (l < nb) {
            zsh[r] = z;
            float* dst = rptr(r) + j0;
            #pragma unroll
            for (int c = 0; c < 32; c++)
                if (c <= l) dst[c] = a[c];
        }
    }
}

// ---------------------------------------------------------------------------
__global__ __launch_bounds__(256, 1) void chol_solve(
    const float* __restrict__ cov, const float* __restrict__ rc,
    const int* __restrict__ obs_idx, const int* __restrict__ n_obs,
    float* __restrict__ gtail_all, float* __restrict__ out) {

    extern __shared__ float smem[];
    float* T    = smem;                         // TRI_FLOATS
    float* zsh  = T + TRI_FLOATS;               // 512
    int*   oi   = (int*)(zsh + 512);            // 512
    float* dinv = (float*)(oi + 512);           // 32
    float* red  = dinv + 32;                    // 8
    float* SB   = red + 8;                      // 64 * SSTR

    int b = blockIdx.x, tid = threadIdx.x;
    int lane = tid & 63, wv = tid >> 6;
    int n = n_obs[b]; if (n > 512) n = 512;
    float* gtail = gtail_all + (size_t)b * GROWS * GSTRIDE;
    if (n == 0) { if (tid == 0) out[b] = 0.f; return; }

    for (int i = tid; i < n; i += 256) {
        oi[i] = obs_idx[b * 512 + i];
        zsh[i] = rc[b * 512 + i];
    }
    __syncthreads();

    int n0 = (n < R0) ? n : R0;

    // gather rows < n0 into LDS triangle (lane = column, ascending oi)
    for (int r = wv; r < n0; r += 4) {
        const float* crow = cov + (size_t)oi[r] * 512;
        float* dst = T + tribase(r);
        for (int j = lane; j <= r; j += 64) dst[j] = crow[oi[j]];
    }
    __syncthreads();

    float llog = 0.f;

    // ================= main in-LDS factorization ==================
    for (int j0 = 0; j0 < n0; j0 += 32) {
        int nb = min(32, n0 - j0);
        diag_block([&](int r) { return T + tribase(r); },
                   zsh, dinv, llog, j0, nb, n0, tid);
        __syncthreads();
        int m = n0 - j0 - 32;
        if (m > 0) {
            // ---- trsm rows + z-update ----
            for (int idx = tid; idx < m; idx += 256) {
                int r = j0 + 32 + idx;
                float* prow = T + tribase(r) + j0;
                float p[32];
                #pragma unroll
                for (int q = 0; q < 8; q++) {
                    float4 t = *(const float4*)&prow[4 * q];
                    p[4*q+0] = t.x; p[4*q+1] = t.y; p[4*q+2] = t.z; p[4*q+3] = t.w;
                }
                #pragma unroll
                for (int j = 0; j < 32; j++) {
                    float acc = p[j];
                    const float* dj = T + tribase(j0 + j) + j0;
                    int jf = j >> 2;
                    for (int q2 = 0; q2 < jf; q2++) {
                        float4 t = *(const float4*)&dj[q2 * 4];
                        acc -= p[q2*4+0]*t.x + p[q2*4+1]*t.y + p[q2*4+2]*t.z + p[q2*4+3]*t.w;
                    }
                    for (int c = jf * 4; c < j; c++) acc -= p[c] * dj[c];
                    p[j] = acc * dinv[j];
                }
                float zu = 0.f;
                #pragma unroll
                for (int q = 0; q < 8; q++) {
                    *(float4*)&prow[4 * q] = make_float4(p[4*q], p[4*q+1], p[4*q+2], p[4*q+3]);
                    float4 zz = *(const float4*)&zsh[j0 + 4 * q];
                    zu += p[4*q]*zz.x + p[4*q+1]*zz.y + p[4*q+2]*zz.z + p[4*q+3]*zz.w;
                }
                zsh[r] -= zu;
            }
            __syncthreads();
            // ---- syrk: 64x64 macros, 16x16 thread grid, 4x4 tiles ----
            int nMac = (m + 63) >> 6;
            int ty = tid >> 4, tx = tid & 15;
            for (int MI = 0; MI < nMac; MI++) {
                for (int MJ = 0; MJ <= MI; MJ++) {
                    int rbase = j0 + 32 + MI * 64 + ty * 4;
                    int cbase = j0 + 32 + MJ * 64 + tx * 4;
                    if (MI == MJ && cbase > rbase + 3) continue;
                    int ra[4], rb[4];
                    #pragma unroll
                    for (int a = 0; a < 4; a++) {
                        ra[a] = tribase(min(rbase + a, n0 - 1)) + j0;
                        rb[a] = tribase(min(cbase + a, n0 - 1)) + j0;
                    }
                    float acc[4][4];
                    #pragma unroll
                    for (int a = 0; a < 4; a++)
                        #pragma unroll
                        for (int c = 0; c < 4; c++) acc[a][c] = 0.f;
                    #pragma unroll
                    for (int q = 0; q < 8; q++) {
                        float4 av[4], bv[4];
                        #pragma unroll
                        for (int a = 0; a < 4; a++) av[a] = *(const float4*)&T[ra[a] + 4 * q];
                        #pragma unroll
                        for (int c = 0; c < 4; c++) bv[c] = *(const float4*)&T[rb[c] + 4 * q];
                        #pragma unroll
                        for (int a = 0; a < 4; a++)
                            #pragma unroll
                            for (int c = 0; c < 4; c++)
                                acc[a][c] += av[a].x*bv[c].x + av[a].y*bv[c].y +
                                             av[a].z*bv[c].z + av[a].w*bv[c].w;
                    }
                    #pragma unroll
                    for (int a = 0; a < 4; a++) {
                        int r = rbase + a;
                        if (r < n0) {
                            float* trow = T + tribase(r);
                            if (cbase + 3 <= r) {
                                float4 v = *(const float4*)&trow[cbase];
                                v.x -= acc[a][0]; v.y -= acc[a][1];
                                v.z -= acc[a][2]; v.w -= acc[a][3];
                                *(float4*)&trow[cbase] = v;
                            } else {
                                #pragma unroll
                                for (int c = 0; c < 4; c++) {
                                    int cl = cbase + c;
                                    if (cl <= r) trow[cl] -= acc[a][c];
                                }
                            }
                        }
                    }
                }
            }
            __syncthreads();
        }
    }

    // ================= bordered tail (rows >= R0) ==================
    for (int gs = R0; gs < n; gs += 64) {
        int t1 = min(64, n - gs);
        int i = tid >> 2, qg = tid & 3;
        float zi = 0.f;
        if (tid < 64 && tid < t1) zi = zsh[gs + tid];

        // ---- W = K21 * L^-T, left-looking over column panels ----
        for (int cp = 0; cp < gs; cp += 32) {
            float acc8[8];
            #pragma unroll
            for (int q = 0; q < 8; q++) acc8[q] = 0.f;
            bool inT = (cp < R0);
            for (int cc = 0; cc < cp; cc += 32) {
                __syncthreads();
                {
                    int f = tid & 7;
                    for (int rr = tid >> 3; rr < t1; rr += 32)
                        *(float4*)&SB[rr * SSTR + f * 4] =
                            *(const float4*)&gtail[(size_t)(gs - R0 + rr) * GSTRIDE + cc + f * 4];
                }
                __syncthreads();
                if (i < t1) {
                    #pragma unroll
                    for (int f = 0; f < 8; f++) {
                        float4 wf = *(const float4*)&SB[i * SSTR + f * 4];
                        #pragma unroll
                        for (int q = 0; q < 8; q++) {
                            int Lr = cp + qg * 8 + q;
                            const float* lr = inT ? (T + tribase(Lr))
                                                  : (gtail + (size_t)(Lr - R0) * GSTRIDE);
                            float4 lf = *(const float4*)&lr[cc + f * 4];
                            acc8[q] += wf.x*lf.x + wf.y*lf.y + wf.z*lf.z + wf.w*lf.w;
                        }
                    }
                }
            }
            __syncthreads();
            if (i < t1) {
                const float* crow = cov + (size_t)oi[gs + i] * 512;
                #pragma unroll
                for (int q = 0; q < 8; q++) {
                    int gq = qg * 8 + q;
                    SB[i * SSTR + gq] = crow[oi[cp + gq]] - acc8[q];
                }
            }
            __syncthreads();
            // trsv vs diag block of panel cp (lane = tail row)
            if (tid < 64 && tid < t1) {
                int l = tid;
                float w[32];
                #pragma unroll
                for (int q = 0; q < 32; q++) w[q] = SB[l * SSTR + q];
                for (int q = 0; q < 32; q++) {
                    const float* lrq = inT ? (T + tribase(cp + q))
                                           : (gtail + (size_t)(cp + q - R0) * GSTRIDE);
                    const float* dq = lrq + cp;
                    float acc = w[q];
                    int qf = q >> 2;
                    for (int q2 = 0; q2 < qf; q2++) {
                        float4 t = *(const float4*)&dq[q2 * 4];
                        acc -= w[q2*4+0]*t.x + w[q2*4+1]*t.y + w[q2*4+2]*t.z + w[q2*4+3]*t.w;
                    }
                    for (int c = qf * 4; c < q; c++) acc -= w[c] * dq[c];
                    w[q] = acc / dq[q];
                    zi -= w[q] * zsh[cp + q];
                }
                float* gw = gtail + (size_t)(gs - R0 + l) * GSTRIDE + cp;
                #pragma unroll
                for (int q = 0; q < 8; q++)
                    *(float4*)&gw[q * 4] = make_float4(w[4*q], w[4*q+1], w[4*q+2], w[4*q+3]);
            }
            __syncthreads();
        }
        if (tid < 64 && tid < t1) zsh[gs + tid] = zi;
        __syncthreads();

        // ---- corner S22 = G22 - W W^T ----
        int npair = t1 * (t1 + 1) / 2;
        {
            float accp[9];
            #pragma unroll
            for (int s = 0; s < 9; s++) accp[s] = 0.f;
            for (int cc = 0; cc < gs; cc += 32) {
                __syncthreads();
                {
                    int f = tid & 7;
                    for (int rr = tid >> 3; rr < t1; rr += 32)
                        *(float4*)&SB[rr * SSTR + f * 4] =
                            *(const float4*)&gtail[(size_t)(gs - R0 + rr) * GSTRIDE + cc + f * 4];
                }
                __syncthreads();
                int slot = 0;
                for (int e = tid; e < npair; e += 256, slot++) {
                    int ti = (int)((sqrtf(8.f * (float)e + 1.f) - 1.f) * 0.5f);
                    while ((ti + 1) * (ti + 2) / 2 <= e) ti++;
                    while (ti * (ti + 1) / 2 > e) ti--;
                    int tj = e - ti * (ti + 1) / 2;
                    const float* wa = &SB[ti * SSTR];
                    const float* wb = &SB[tj * SSTR];
                    float s = accp[slot];
                    #pragma unroll
                    for (int f = 0; f < 8; f++) {
                        float4 a4 = *(const float4*)&wa[f * 4];
                        float4 b4 = *(const float4*)&wb[f * 4];
                        s += a4.x*b4.x + a4.y*b4.y + a4.z*b4.z + a4.w*b4.w;
                    }
                    accp[slot] = s;
                }
            }
            __syncthreads();
            int slot = 0;
            for (int e = tid; e < npair; e += 256, slot++) {
                int ti = (int)((sqrtf(8.f * (float)e + 1.f) - 1.f) * 0.5f);
                while ((ti + 1) * (ti + 2) / 2 <= e) ti++;
                while (ti * (ti + 1) / 2 > e) ti--;
                int tj = e - ti * (ti + 1) / 2;
                float g = cov[(size_t)oi[gs + ti] * 512 + oi[gs + tj]];
                gtail[(size_t)(gs - R0 + ti) * GSTRIDE + gs + tj] = g - accp[slot];
            }
            __syncthreads();
        }

        // ---- factor corner ----
        diag_block([&](int r) { return gtail + (size_t)(r - R0) * GSTRIDE; },
                   zsh, dinv, llog, gs, min(32, t1), n, tid);
        __syncthreads();
        if (t1 > 32) {
            int t2 = t1 - 32;
            if (tid < t2) {
                int r = gs + 32 + tid;
                float* grow = gtail + (size_t)(r - R0) * GSTRIDE + gs;
                float p[32];
                #pragma unroll
                for (int q = 0; q < 8; q++) {
                    float4 t = *(const float4*)&grow[4 * q];
                    p[4*q+0] = t.x; p[4*q+1] = t.y; p[4*q+2] = t.z; p[4*q+3] = t.w;
                }
                #pragma unroll
                for (int j = 0; j < 32; j++) {
                    float acc = p[j];
                    const float* dj = gtail + (size_t)(gs + j - R0) * GSTRIDE + gs;
                    int jf = j >> 2;
                    for (int q2 = 0; q2 < jf; q2++) {
                        float4 t = *(const float4*)&dj[q2 * 4];
                        acc -= p[q2*4+0]*t.x + p[q2*4+1]*t.y + p[q2*4+2]*t.z + p[q2*4+3]*t.w;
                    }
                    for (int c = jf * 4; c < j; c++) acc -= p[c] * dj[c];
                    p[j] = acc * dinv[j];
                }
                float zu = 0.f;
                #pragma unroll
                for (int q = 0; q < 8; q++) {
                    *(float4*)&grow[4 * q] = make_float4(p[4*q], p[4*q+1], p[4*q+2], p[4*q+3]);
                    SB[tid * SSTR + 4*q+0] = p[4*q+0]; SB[tid * SSTR + 4*q+1] = p[4*q+1];
                    SB[tid * SSTR + 4*q+2] = p[4*q+2]; SB[tid * SSTR + 4*q+3] = p[4*q+3];
                    float4 zz = *(const float4*)&zsh[gs + 4 * q];
                    zu += p[4*q]*zz.x + p[4*q+1]*zz.y + p[4*q+2]*zz.z + p[4*q+3]*zz.w;
                }
                zsh[r] -= zu;
            }
            __syncthreads();
            int np2 = t2 * (t2 + 1) / 2;
            for (int e = tid; e < np2; e += 256) {
                int ti = (int)((sqrtf(8.f * (float)e + 1.f) - 1.f) * 0.5f);
                while ((ti + 1) * (ti + 2) / 2 <= e) ti++;
                while (ti * (ti + 1) / 2 > e) ti--;
                int tj = e - ti * (ti + 1) / 2;
                const float* wa = &SB[ti * SSTR];
                const float* wb = &SB[tj * SSTR];
                float s = 0.f;
                #pragma unroll
                for (int f = 0; f < 8; f++) {
                    float4 a4 = *(const float4*)&wa[f * 4];
                    float4 b4 = *(const float4*)&wb[f * 4];
                    s += a4.x*b4.x + a4.y*b4.y + a4.z*b4.z + a4.w*b4.w;
                }
                gtail[(size_t)(gs + 32 + ti - R0) * GSTRIDE + gs + 32 + tj] -= s;
            }
            __syncthreads();
            diag_block([&](int r) { return gtail + (size_t)(r - R0) * GSTRIDE; },
                       zsh, dinv, llog, gs + 32, min(32, t2), n, tid);
            __syncthreads();
        }
    }

    // ================= epilogue ==================
    float q = 0.f;
    for (int ii = tid; ii < n; ii += 256) { float zv = zsh[ii]; q += zv * zv; }
    #pragma unroll
    for (int off = 32; off; off >>= 1) {
        q    += __shfl_down(q, off, 64);
        llog += __shfl_down(llog, off, 64);
    }
    if (lane == 0) { red[wv] = q; red[4 + wv] = llog; }
    __syncthreads();
    if (tid == 0) {
        float qt = red[0] + red[1] + red[2] + red[3];
        float ls = red[4] + red[5] + red[6] + red[7];
        out[b] = 0.5f * (qt + 2.f * ls + (float)n * LOG_2PI);
    }
}

// ---------------------------------------------------------------------------
extern "C" void kernel_launch(void* const* d_in, const int* in_sizes, int n_in,
                              void* d_out, int out_size, void* d_ws, size_t ws_size,
                              hipStream_t stream) {
    const float* x    = (const float*)d_in[0];
    const float* mu   = (const float*)d_in[1];
    const float* logd = (const float*)d_in[2];
    const float* lt   = (const float*)d_in[3];
    const int*   mask = (const int*)d_in[4];
    float* out = (float*)d_out;

    char* ws = (char*)d_ws;
    float* cov     = (float*)(ws);
    float* A       = (float*)(ws + 1048576);
    int*   n_obs   = (int*)  (ws + 2097152);
    int*   obs_idx = (int*)  (ws + 2098176);
    float* rc      = (float*)(ws + 2622464);
    float* gtail   = (float*)(ws + 3146752);

    (void)hipFuncSetAttribute((const void*)chol_solve,
                              hipFuncAttributeMaxDynamicSharedMemorySize,
                              SMEM_BYTES);

    build_A<<<1024, 256, 0, stream>>>(logd, lt, A);
    aat64<<<36, 256, 0, stream>>>(A, cov);
    compact<<<256, 256, 0, stream>>>(x, mu, mask, obs_idx, n_obs, rc);
    chol_solve<<<256, 256, SMEM_BYTES, stream>>>(cov, rc, obs_idx, n_obs, gtail, out);
}

// Round 5
// 564.100 us; speedup vs baseline: 1.1789x; 1.0570x over previous
//
#include <hip/hip_runtime.h>
#include <hip/hip_bf16.h>

#define LOG_2PI 1.8378770664093453f
#define R0 256        // rows resident in LDS triangle
#define GSTRIDE 512   // floats per global tail row
#define GROWS 256
#define TRI_FLOATS 33280       // tribase(256)
#define SSTR 36                // staging row stride (16B aligned)
#define NT 512                 // threads per chol_solve block (8 waves)
#define SMEM_FLOATS (TRI_FLOATS + 512 + 512 + 32 + 16 + 64*SSTR)
#define SMEM_BYTES (SMEM_FLOATS * 4)   // 146624

// packed triangle: row r at [tribase(r)], padded to 16B-aligned row starts
__device__ __forceinline__ int tribase(int r) {
    int m = r & 3;
    return r * (r + 1) / 2 + 6 * (r >> 2) + ((m * (7 - m)) >> 1);
}

// ---------------------------------------------------------------------------
__global__ __launch_bounds__(256) void build_A(const float* __restrict__ logd,
                                               const float* __restrict__ lt,
                                               float* __restrict__ A) {
    int idx = blockIdx.x * 256 + threadIdx.x;
    int i = idx >> 9, j = idx & 511;
    float v;
    if (j < i)       v = lt[(i * (i - 1)) / 2 + j];
    else if (j == i) v = expf(logd[i]);
    else             v = 0.f;
    A[idx] = v;
}

// cov = A A^T (512x512), 32x32 tiles, 256 blocks -> all CUs busy.
__global__ __launch_bounds__(256) void aat(const float* __restrict__ A,
                                           float* __restrict__ C) {
    __shared__ float Ash[32][33];
    __shared__ float Bsh[32][33];
    int tx = threadIdx.x & 31, ty = threadIdx.x >> 5;
    int bi = blockIdx.y, bj = blockIdx.x;
    float acc[4] = {0.f, 0.f, 0.f, 0.f};
    for (int k0 = 0; k0 < 512; k0 += 32) {
        #pragma unroll
        for (int q = 0; q < 4; q++) {
            int r = ty + q * 8;
            Ash[r][tx] = A[(bi * 32 + r) * 512 + k0 + tx];
            Bsh[r][tx] = A[(bj * 32 + r) * 512 + k0 + tx];
        }
        __syncthreads();
        for (int c = 0; c < 32; c++) {
            float bv = Bsh[tx][c];
            #pragma unroll
            for (int q = 0; q < 4; q++) acc[q] += Ash[ty + q * 8][c] * bv;
        }
        __syncthreads();
    }
    #pragma unroll
    for (int q = 0; q < 4; q++)
        C[(bi * 32 + ty + q * 8) * 512 + bj * 32 + tx] = acc[q];
}

__global__ __launch_bounds__(256) void compact(const float* __restrict__ x,
                                               const float* __restrict__ mu,
                                               const int* __restrict__ mask,
                                               int* __restrict__ obs_idx,
                                               int* __restrict__ n_obs,
                                               float* __restrict__ rc) {
    int b = blockIdx.x, t = threadIdx.x;
    __shared__ int wsum[4];
    int i0 = 2 * t, i1 = 2 * t + 1;
    int m0 = (mask[b * 512 + i0] != 0) ? 1 : 0;
    int m1 = (mask[b * 512 + i1] != 0) ? 1 : 0;
    int local = m0 + m1;
    int v = local;
    int lane = t & 63, wv = t >> 6;
    #pragma unroll
    for (int off = 1; off < 64; off <<= 1) {
        int u = __shfl_up(v, off, 64);
        if (lane >= off) v += u;
    }
    if (lane == 63) wsum[wv] = v;
    __syncthreads();
    int woff = 0;
    for (int w = 0; w < wv; w++) woff += wsum[w];
    int excl = woff + v - local;
    if (m0) { obs_idx[b * 512 + excl] = i0; rc[b * 512 + excl] = x[b * 512 + i0] - mu[i0]; }
    if (m1) { int p = excl + m0; obs_idx[b * 512 + p] = i1; rc[b * 512 + p] = x[b * 512 + i1] - mu[i1]; }
    if (t == 0) n_obs[b] = wsum[0] + wsum[1] + wsum[2] + wsum[3];
}

// ---------------------------------------------------------------------------
// Diag-block Cholesky + z-panel solve, wave0 lanes 0..31.
// ---------------------------------------------------------------------------
template <typename RPF>
__device__ __forceinline__ void diag_block(RPF rptr, float* zsh, float* dinv,
                                           float& llog, int j0, int nb, int n, int tid) {
    if (tid < 32) {
        int l = tid;
        int r = j0 + l;
        float a[32];
        float z = 0.f;
        if (r < n) {
            const float4* src = (const float4*)(rptr(r) + j0);
            #pragma unroll
            for (int q = 0; q < 8; q++) {
                float4 t = src[q];
                a[4*q+0] = t.x; a[4*q+1] = t.y; a[4*q+2] = t.z; a[4*q+3] = t.w;
            }
            z = zsh[r];
        } else {
            #pragma unroll
            for (int q = 0; q < 32; q++) a[q] = 0.f;
        }
        float dv = 0.f;
        #pragma unroll
        for (int k = 0; k < 32; k++) {
            if (k < nb) {
                float akk = __shfl(a[k], k, 64);
                float lkk = sqrtf(akk);
                float rin = 1.f / lkk;
                if (l == k) { dv = rin; llog += logf(lkk); }
                a[k] = (l == k) ? lkk : a[k] * rin;
                #pragma unroll
                for (int j = k + 1; j < 32; j++) {
                    float ajk = __shfl(a[k], j, 64);
                    a[j] -= a[k] * ajk;
                }
            }
        }
        #pragma unroll
        for (int k = 0; k < 32; k++) {
            if (k < nb) {
                if (l == k) z *= dv;
                float zk = __shfl(z, k, 64);
                if (l > k) z -= a[k] * zk;
            }
        }
        dinv[l] = dv;
        if (l < nb) {
            zsh[r] = z;
            float* dst = rptr(r) + j0;
            #pragma unroll
            for (int c = 0; c < 32; c++)
                if (c <= l) dst[c] = a[c];
        }
    }
}

// ---------------------------------------------------------------------------
__global__ __launch_bounds__(NT, 2) void chol_solve(
    const float* __restrict__ cov, const float* __restrict__ rc,
    const int* __restrict__ obs_idx, const int* __restrict__ n_obs,
    float* __restrict__ gtail_all, float* __restrict__ out) {

    extern __shared__ float smem[];
    float* T    = smem;                         // TRI_FLOATS
    float* zsh  = T + TRI_FLOATS;               // 512
    int*   oi   = (int*)(zsh + 512);            // 512
    float* dinv = (float*)(oi + 512);           // 32
    float* red  = dinv + 32;                    // 16
    float* SB   = red + 16;                     // 64 * SSTR

    int b = blockIdx.x, tid = threadIdx.x;
    int lane = tid & 63, wv = tid >> 6;         // wv in [0,8)
    int n = n_obs[b]; if (n > 512) n = 512;
    float* gtail = gtail_all + (size_t)b * GROWS * GSTRIDE;
    if (n == 0) { if (tid == 0) out[b] = 0.f; return; }

    for (int i = tid; i < n; i += NT) {
        oi[i] = obs_idx[b * 512 + i];
        zsh[i] = rc[b * 512 + i];
    }
    __syncthreads();

    int n0 = (n < R0) ? n : R0;

    // gather rows < n0 into LDS triangle (lane = column, ascending oi)
    for (int r = wv; r < n0; r += 8) {
        const float* crow = cov + (size_t)oi[r] * 512;
        float* dst = T + tribase(r);
        for (int j = lane; j <= r; j += 64) dst[j] = crow[oi[j]];
    }
    __syncthreads();

    float llog = 0.f;

    // ================= main in-LDS factorization ==================
    for (int j0 = 0; j0 < n0; j0 += 32) {
        int nb = min(32, n0 - j0);
        diag_block([&](int r) { return T + tribase(r); },
                   zsh, dinv, llog, j0, nb, n0, tid);
        __syncthreads();
        int m = n0 - j0 - 32;
        if (m > 0) {
            // ---- trsm rows + z-update ----
            for (int idx = tid; idx < m; idx += NT) {
                int r = j0 + 32 + idx;
                float* prow = T + tribase(r) + j0;
                float p[32];
                #pragma unroll
                for (int q = 0; q < 8; q++) {
                    float4 t = *(const float4*)&prow[4 * q];
                    p[4*q+0] = t.x; p[4*q+1] = t.y; p[4*q+2] = t.z; p[4*q+3] = t.w;
                }
                #pragma unroll
                for (int j = 0; j < 32; j++) {
                    float acc = p[j];
                    const float* dj = T + tribase(j0 + j) + j0;
                    int jf = j >> 2;
                    for (int q2 = 0; q2 < jf; q2++) {
                        float4 t = *(const float4*)&dj[q2 * 4];
                        acc -= p[q2*4+0]*t.x + p[q2*4+1]*t.y + p[q2*4+2]*t.z + p[q2*4+3]*t.w;
                    }
                    for (int c = jf * 4; c < j; c++) acc -= p[c] * dj[c];
                    p[j] = acc * dinv[j];
                }
                float zu = 0.f;
                #pragma unroll
                for (int q = 0; q < 8; q++) {
                    *(float4*)&prow[4 * q] = make_float4(p[4*q], p[4*q+1], p[4*q+2], p[4*q+3]);
                    float4 zz = *(const float4*)&zsh[j0 + 4 * q];
                    zu += p[4*q]*zz.x + p[4*q+1]*zz.y + p[4*q+2]*zz.z + p[4*q+3]*zz.w;
                }
                zsh[r] -= zu;
            }
            __syncthreads();
            // ---- syrk: 64x64 macro pairs, 2 concurrent 256-thread groups ----
            int nMac = (m + 63) >> 6;
            int nPairs = nMac * (nMac + 1) / 2;
            int grp = tid >> 8;                 // 0 or 1
            int sub = tid & 255;
            int ty = sub >> 4, tx = sub & 15;
            for (int e = grp; e < nPairs; e += 2) {
                int MI = 0;
                while ((MI + 1) * (MI + 2) / 2 <= e) MI++;
                int MJ = e - MI * (MI + 1) / 2;
                int rbase = j0 + 32 + MI * 64 + ty * 4;
                int cbase = j0 + 32 + MJ * 64 + tx * 4;
                if (MI == MJ && cbase > rbase + 3) continue;
                int ra[4], rb[4];
                #pragma unroll
                for (int a = 0; a < 4; a++) {
                    ra[a] = tribase(min(rbase + a, n0 - 1)) + j0;
                    rb[a] = tribase(min(cbase + a, n0 - 1)) + j0;
                }
                float acc[4][4];
                #pragma unroll
                for (int a = 0; a < 4; a++)
                    #pragma unroll
                    for (int c = 0; c < 4; c++) acc[a][c] = 0.f;
                #pragma unroll
                for (int q = 0; q < 8; q++) {
                    float4 av[4], bv[4];
                    #pragma unroll
                    for (int a = 0; a < 4; a++) av[a] = *(const float4*)&T[ra[a] + 4 * q];
                    #pragma unroll
                    for (int c = 0; c < 4; c++) bv[c] = *(const float4*)&T[rb[c] + 4 * q];
                    #pragma unroll
                    for (int a = 0; a < 4; a++)
                        #pragma unroll
                        for (int c = 0; c < 4; c++)
                            acc[a][c] += av[a].x*bv[c].x + av[a].y*bv[c].y +
                                         av[a].z*bv[c].z + av[a].w*bv[c].w;
                }
                #pragma unroll
                for (int a = 0; a < 4; a++) {
                    int r = rbase + a;
                    if (r < n0) {
                        float* trow = T + tribase(r);
                        if (cbase + 3 <= r) {
                            float4 v = *(const float4*)&trow[cbase];
                            v.x -= acc[a][0]; v.y -= acc[a][1];
                            v.z -= acc[a][2]; v.w -= acc[a][3];
                            *(float4*)&trow[cbase] = v;
                        } else {
                            #pragma unroll
                            for (int c = 0; c < 4; c++) {
                                int cl = cbase + c;
                                if (cl <= r) trow[cl] -= acc[a][c];
                            }
                        }
                    }
                }
            }
            __syncthreads();
        }
    }

    // ================= bordered tail (rows >= R0) ==================
    for (int gs = R0; gs < n; gs += 64) {
        int t1 = min(64, n - gs);
        int i = tid >> 3, qg = tid & 7;         // i in [0,64), qg: 4-col group
        float zi = 0.f;
        if (tid < 64 && tid < t1) zi = zsh[gs + tid];

        // ---- W = K21 * L^-T, left-looking over column panels ----
        for (int cp = 0; cp < gs; cp += 32) {
            float acc4[4];
            #pragma unroll
            for (int q = 0; q < 4; q++) acc4[q] = 0.f;
            bool inT = (cp < R0);
            for (int cc = 0; cc < cp; cc += 32) {
                __syncthreads();
                {
                    int f = tid & 7, rr = tid >> 3;
                    if (rr < t1)
                        *(float4*)&SB[rr * SSTR + f * 4] =
                            *(const float4*)&gtail[(size_t)(gs - R0 + rr) * GSTRIDE + cc + f * 4];
                }
                __syncthreads();
                if (i < t1) {
                    #pragma unroll
                    for (int f = 0; f < 8; f++) {
                        float4 wf = *(const float4*)&SB[i * SSTR + f * 4];
                        #pragma unroll
                        for (int q = 0; q < 4; q++) {
                            int Lr = cp + qg * 4 + q;
                            const float* lr = inT ? (T + tribase(Lr))
                                                  : (gtail + (size_t)(Lr - R0) * GSTRIDE);
                            float4 lf = *(const float4*)&lr[cc + f * 4];
                            acc4[q] += wf.x*lf.x + wf.y*lf.y + wf.z*lf.z + wf.w*lf.w;
                        }
                    }
                }
            }
            __syncthreads();
            if (i < t1) {
                const float* crow = cov + (size_t)oi[gs + i] * 512;
                #pragma unroll
                for (int q = 0; q < 4; q++) {
                    int gq = qg * 4 + q;
                    SB[i * SSTR + gq] = crow[oi[cp + gq]] - acc4[q];
                }
            }
            __syncthreads();
            // trsv vs diag block of panel cp (lane = tail row)
            if (tid < 64 && tid < t1) {
                int l = tid;
                float w[32];
                #pragma unroll
                for (int q = 0; q < 32; q++) w[q] = SB[l * SSTR + q];
                for (int q = 0; q < 32; q++) {
                    const float* lrq = inT ? (T + tribase(cp + q))
                                           : (gtail + (size_t)(cp + q - R0) * GSTRIDE);
                    const float* dq = lrq + cp;
                    float acc = w[q];
                    int qf = q >> 2;
                    for (int q2 = 0; q2 < qf; q2++) {
                        float4 t = *(const float4*)&dq[q2 * 4];
                        acc -= w[q2*4+0]*t.x + w[q2*4+1]*t.y + w[q2*4+2]*t.z + w[q2*4+3]*t.w;
                    }
                    for (int c = qf * 4; c < q; c++) acc -= w[c] * dq[c];
                    w[q] = acc / dq[q];
                    zi -= w[q] * zsh[cp + q];
                }
                float* gw = gtail + (size_t)(gs - R0 + l) * GSTRIDE + cp;
                #pragma unroll
                for (int q = 0; q < 8; q++)
                    *(float4*)&gw[q * 4] = make_float4(w[4*q], w[4*q+1], w[4*q+2], w[4*q+3]);
            }
            __syncthreads();
        }
        if (tid < 64 && tid < t1) zsh[gs + tid] = zi;
        __syncthreads();

        // ---- corner S22 = G22 - W W^T ----
        int npair = t1 * (t1 + 1) / 2;
        {
            float accp[5];
            #pragma unroll
            for (int s = 0; s < 5; s++) accp[s] = 0.f;
            for (int cc = 0; cc < gs; cc += 32) {
                __syncthreads();
                {
                    int f = tid & 7, rr = tid >> 3;
                    if (rr < t1)
                        *(float4*)&SB[rr * SSTR + f * 4] =
                            *(const float4*)&gtail[(size_t)(gs - R0 + rr) * GSTRIDE + cc + f * 4];
                }
                __syncthreads();
                int slot = 0;
                for (int e = tid; e < npair; e += NT, slot++) {
                    int ti = (int)((sqrtf(8.f * (float)e + 1.f) - 1.f) * 0.5f);
                    while ((ti + 1) * (ti + 2) / 2 <= e) ti++;
                    while (ti * (ti + 1) / 2 > e) ti--;
                    int tj = e - ti * (ti + 1) / 2;
                    const float* wa = &SB[ti * SSTR];
                    const float* wb = &SB[tj * SSTR];
                    float s = accp[slot];
                    #pragma unroll
                    for (int f = 0; f < 8; f++) {
                        float4 a4 = *(const float4*)&wa[f * 4];
                        float4 b4 = *(const float4*)&wb[f * 4];
                        s += a4.x*b4.x + a4.y*b4.y + a4.z*b4.z + a4.w*b4.w;
                    }
                    accp[slot] = s;
                }
            }
            __syncthreads();
            int slot = 0;
            for (int e = tid; e < npair; e += NT, slot++) {
                int ti = (int)((sqrtf(8.f * (float)e + 1.f) - 1.f) * 0.5f);
                while ((ti + 1) * (ti + 2) / 2 <= e) ti++;
                while (ti * (ti + 1) / 2 > e) ti--;
                int tj = e - ti * (ti + 1) / 2;
                float g = cov[(size_t)oi[gs + ti] * 512 + oi[gs + tj]];
                gtail[(size_t)(gs - R0 + ti) * GSTRIDE + gs + tj] = g - accp[slot];
            }
            __syncthreads();
        }

        // ---- factor corner ----
        diag_block([&](int r) { return gtail + (size_t)(r - R0) * GSTRIDE; },
                   zsh, dinv, llog, gs, min(32, t1), n, tid);
        __syncthreads();
        if (t1 > 32) {
            int t2 = t1 - 32;
            if (tid < t2) {
                int r = gs + 32 + tid;
                float* grow = gtail + (size_t)(r - R0) * GSTRIDE + gs;
                float p[32];
                #pragma unroll
                for (int q = 0; q < 8; q++) {
                    float4 t = *(const float4*)&grow[4 * q];
                    p[4*q+0] = t.x; p[4*q+1] = t.y; p[4*q+2] = t.z; p[4*q+3] = t.w;
                }
                #pragma unroll
                for (int j = 0; j < 32; j++) {
                    float acc = p[j];
                    const float* dj = gtail + (size_t)(gs + j - R0) * GSTRIDE + gs;
                    int jf = j >> 2;
                    for (int q2 = 0; q2 < jf; q2++) {
                        float4 t = *(const float4*)&dj[q2 * 4];
                        acc -= p[q2*4+0]*t.x + p[q2*4+1]*t.y + p[q2*4+2]*t.z + p[q2*4+3]*t.w;
                    }
                    for (int c = jf * 4; c < j; c++) acc -= p[c] * dj[c];
                    p[j] = acc * dinv[j];
                }
                float zu = 0.f;
                #pragma unroll
                for (int q = 0; q < 8; q++) {
                    *(float4*)&grow[4 * q] = make_float4(p[4*q], p[4*q+1], p[4*q+2], p[4*q+3]);
                    SB[tid * SSTR + 4*q+0] = p[4*q+0]; SB[tid * SSTR + 4*q+1] = p[4*q+1];
                    SB[tid * SSTR + 4*q+2] = p[4*q+2]; SB[tid * SSTR + 4*q+3] = p[4*q+3];
                    float4 zz = *(const float4*)&zsh[gs + 4 * q];
                    zu += p[4*q]*zz.x + p[4*q+1]*zz.y + p[4*q+2]*zz.z + p[4*q+3]*zz.w;
                }
                zsh[r] -= zu;
            }
            __syncthreads();
            int np2 = t2 * (t2 + 1) / 2;
            for (int e = tid; e < np2; e += NT) {
                int ti = (int)((sqrtf(8.f * (float)e + 1.f) - 1.f) * 0.5f);
                while ((ti + 1) * (ti + 2) / 2 <= e) ti++;
                while (ti * (ti + 1) / 2 > e) ti--;
                int tj = e - ti * (ti + 1) / 2;
                const float* wa = &SB[ti * SSTR];
                const float* wb = &SB[tj * SSTR];
                float s = 0.f;
                #pragma unroll
                for (int f = 0; f < 8; f++) {
                    float4 a4 = *(const float4*)&wa[f * 4];
                    float4 b4 = *(const float4*)&wb[f * 4];
                    s += a4.x*b4.x + a4.y*b4.y + a4.z*b4.z + a4.w*b4.w;
                }
                gtail[(size_t)(gs + 32 + ti - R0) * GSTRIDE + gs + 32 + tj] -= s;
            }
            __syncthreads();
            diag_block([&](int r) { return gtail + (size_t)(r - R0) * GSTRIDE; },
                       zsh, dinv, llog, gs + 32, min(32, t2), n, tid);
            __syncthreads();
        }
    }

    // ================= epilogue ==================
    float q = 0.f;
    for (int ii = tid; ii < n; ii += NT) { float zv = zsh[ii]; q += zv * zv; }
    #pragma unroll
    for (int off = 32; off; off >>= 1) {
        q    += __shfl_down(q, off, 64);
        llog += __shfl_down(llog, off, 64);
    }
    if (lane == 0) { red[wv] = q; red[8 + wv] = llog; }
    __syncthreads();
    if (tid == 0) {
        float qt = 0.f, ls = 0.f;
        #pragma unroll
        for (int w = 0; w < 8; w++) { qt += red[w]; ls += red[8 + w]; }
        out[b] = 0.5f * (qt + 2.f * ls + (float)n * LOG_2PI);
    }
}

// ---------------------------------------------------------------------------
extern "C" void kernel_launch(void* const* d_in, const int* in_sizes, int n_in,
                              void* d_out, int out_size, void* d_ws, size_t ws_size,
                              hipStream_t stream) {
    const float* x    = (const float*)d_in[0];
    const float* mu   = (const float*)d_in[1];
    const float* logd = (const float*)d_in[2];
    const float* lt   = (const float*)d_in[3];
    const int*   mask = (const int*)d_in[4];
    float* out = (float*)d_out;

    char* ws = (char*)d_ws;
    float* cov     = (float*)(ws);
    float* A       = (float*)(ws + 1048576);
    int*   n_obs   = (int*)  (ws + 2097152);
    int*   obs_idx = (int*)  (ws + 2098176);
    float* rc      = (float*)(ws + 2622464);
    float* gtail   = (float*)(ws + 3146752);

    (void)hipFuncSetAttribute((const void*)chol_solve,
                              hipFuncAttributeMaxDynamicSharedMemorySize,
                              SMEM_BYTES);

    build_A<<<1024, 256, 0, stream>>>(logd, lt, A);
    dim3 g(16, 16);
    aat<<<g, 256, 0, stream>>>(A, cov);
    compact<<<256, 256, 0, stream>>>(x, mu, mask, obs_idx, n_obs, rc);
    chol_solve<<<256, NT, SMEM_BYTES, stream>>>(cov, rc, obs_idx, n_obs, gtail, out);
}